// Round 7
// baseline (119.662 us; speedup 1.0000x reference)
//
#include <hip/hip_runtime.h>

#define NGAUSS 2048
#define NPIX   65536
#define WID    512.0f
#define HEI    512.0f
#define TPB    1024               // 16 waves per block
#define NWAVE  16
#define NSLICE 32                 // total gaussian slices (2 blocks x 16 waves)
#define GPW    (NGAUSS / NSLICE)  // 64 gaussians per wave
#define GPB    (NGAUSS / 2)       // 1024 gaussians staged per block (its half)
#define PPW    512                // pixels per wave: 64 lanes x 8 (4 v2f pairs)
#define NPG    (NPIX / PPW)       // 128 pixel groups
#define NBLK   (NPG * 2)          // 256 blocks = 1/CU = 16 waves/CU

typedef float v2f __attribute__((ext_vector_type(2)));

// Block (pg, half): stages its OWN 1024-gaussian half into LDS (36 KiB),
// 16 waves share the same 512 pixels (8/thread, packed v2f), wave w covers
// gaussians [half*1024 + w*64, +64). In-block LDS reduction, then ONE
// global atomicAdd per reduced output element (2 blocks/pixel-group ->
// 393K atomics total ~ 4.7 MB, vs R5's 6.3M).
// Per-CU LDS pipe demand: 1024 iter x ~30cyc = ~13 us (was ~51 in R6).
// dx = A*X + B*Y + E0 ; dy = C*X + D*Y + E1 ; w = exp2(-(dx^2+dy^2))
// A..E pre-scaled by sqrt(log2(e)) so exp(-q) == exp2(-q_scaled).

static __device__ __forceinline__ v2f splat2(float s) { return (v2f){s, s}; }

// fast transcendentals on the hardware pipes (prep only; ~1e-6 abs err)
static __device__ __forceinline__ float fast_exp(float z) {
    return __builtin_amdgcn_exp2f(1.44269504f * z);
}
static __device__ __forceinline__ float fast_sigmoid(float z) {
    return __builtin_amdgcn_rcpf(1.0f + fast_exp(-z));
}
static __device__ __forceinline__ float fast_tanh(float z) {
    return 2.0f * __builtin_amdgcn_rcpf(1.0f + fast_exp(-2.0f * z)) - 1.0f;
}

__global__ __launch_bounds__(TPB, 4) void splat_kernel(
    const float2* __restrict__ x, const float* __restrict__ rgb,
    const float* __restrict__ mu, const float* __restrict__ scale,
    const float* __restrict__ angle, float* __restrict__ out)
{
    __shared__ float4 smA[GPB];        // (A,B,C,D)    16 KiB
    __shared__ float4 smB[GPB];        // (E0,E1,r,g)  16 KiB
    __shared__ float  smC[GPB];        // b             4 KiB
    __shared__ float  smOut[PPW * 3];  // reduction     6 KiB

    const int tid  = threadIdx.x;
    // pair blocks 128 apart: same XCD under %8 round-robin -> shared out
    // lines stay in one L2
    const int pg   = blockIdx.x & (NPG - 1);
    const int half = blockIdx.x >> 7;

    // ---- fused prep: 1 gaussian per thread (this block's half only) ----
    {
        const int n = half * GPB + tid;   // global gaussian id
        const float MU_BORDER = 1.05f;
        const float S_MIN = 1.0f / 30.0f;
        const float S_MAX = 1.0f / 0.75f;
        const float PI_APPROX = 3.1416f;
        const float K = 1.2011224087864498f;  // sqrt(log2(e))
        const float INV2PI = 0.15915494309f;

        float mx = fast_tanh(mu[2*n+0]) * MU_BORDER * (0.5f * WID);
        float my = fast_tanh(mu[2*n+1]) * MU_BORDER * (0.5f * HEI);
        float al = fast_tanh(angle[n]) * PI_APPROX;
        float c = __builtin_amdgcn_cosf(al * INV2PI);  // v_cos: revolutions
        float s = __builtin_amdgcn_sinf(al * INV2PI);
        float S0 = fast_sigmoid(scale[2*n+0]) * (S_MAX - S_MIN) + S_MIN;
        float S1 = fast_sigmoid(scale[2*n+1]) * (S_MAX - S_MIN) + S_MIN;

        float A  =  S0 * c * K;
        float Bc = -(S0 * s * K);
        float C  =  S1 * s * K;
        float D  =  S1 * c * K;
        float E0 = -(A * mx + Bc * my);
        float E1 = -(C * mx + D  * my);

        smA[tid] = make_float4(A, Bc, C, D);
        smB[tid] = make_float4(E0, E1,
                               fast_sigmoid(rgb[3*n+0]),
                               fast_sigmoid(rgb[3*n+1]));
        smC[tid] = fast_sigmoid(rgb[3*n+2]);
    }
    // zero the reduction buffer
    for (int i = tid; i < PPW * 3; i += TPB) smOut[i] = 0.f;

    // ---- pixel load: all waves share the same 512 pixels, 8 per lane ----
    const int lane   = tid & 63;
    const int wave   = tid >> 6;
    const int pxbase = pg * PPW;
    v2f PX[4], PY[4];
    #pragma unroll
    for (int k = 0; k < 4; ++k) {
        float2 a = x[pxbase + (2*k+0) * 64 + lane];
        float2 b = x[pxbase + (2*k+1) * 64 + lane];
        PX[k] = (v2f){a.x - 0.5f * WID, b.x - 0.5f * WID};
        PY[k] = (v2f){a.y - 0.5f * HEI, b.y - 0.5f * HEI};
    }

    __syncthreads();

    // ---- main loop: this wave's 64-gaussian slice, broadcast LDS reads ----
    const int gbase = wave * GPW;   // index into the staged half
    v2f ar[4], ag[4], ab[4];
    #pragma unroll
    for (int k = 0; k < 4; ++k) {
        ar[k] = (v2f){0.f, 0.f}; ag[k] = (v2f){0.f, 0.f}; ab[k] = (v2f){0.f, 0.f};
    }

    #pragma unroll 4
    for (int j = 0; j < GPW; ++j) {
        float4 c0 = smA[gbase + j];   // A,B,C,D
        float4 c1 = smB[gbase + j];   // E0,E1,r,g
        float  cb = smC[gbase + j];   // b
        #pragma unroll
        for (int k = 0; k < 4; ++k) {
            v2f dx = __builtin_elementwise_fma(splat2(c0.x), PX[k],
                       __builtin_elementwise_fma(splat2(c0.y), PY[k], splat2(c1.x)));
            v2f dy = __builtin_elementwise_fma(splat2(c0.z), PX[k],
                       __builtin_elementwise_fma(splat2(c0.w), PY[k], splat2(c1.y)));
            v2f q  = __builtin_elementwise_fma(dx, dx, dy * dy);
            v2f w;
            w.x = __builtin_amdgcn_exp2f(-q.x);
            w.y = __builtin_amdgcn_exp2f(-q.y);
            ar[k] = __builtin_elementwise_fma(w, splat2(c1.z), ar[k]);
            ag[k] = __builtin_elementwise_fma(w, splat2(c1.w), ag[k]);
            ab[k] = __builtin_elementwise_fma(w, splat2(cb),   ab[k]);
        }
    }

    // ---- in-block reduction across 16 wave-slices (LDS f32 atomics) ----
    #pragma unroll
    for (int k = 0; k < 4; ++k) {
        int p0 = (2*k+0) * 64 + lane;
        int p1 = (2*k+1) * 64 + lane;
        atomicAdd(&smOut[3*p0 + 0], ar[k].x);
        atomicAdd(&smOut[3*p0 + 1], ag[k].x);
        atomicAdd(&smOut[3*p0 + 2], ab[k].x);
        atomicAdd(&smOut[3*p1 + 0], ar[k].y);
        atomicAdd(&smOut[3*p1 + 1], ag[k].y);
        atomicAdd(&smOut[3*p1 + 2], ab[k].y);
    }
    __syncthreads();

    // ---- combine the 2 blocks of this pixel group via global atomics ----
    #pragma unroll
    for (int i = tid; i < PPW * 3; i += TPB)
        atomicAdd(&out[pxbase * 3 + i], smOut[i]);
}

extern "C" void kernel_launch(void* const* d_in, const int* in_sizes, int n_in,
                              void* d_out, int out_size, void* d_ws, size_t ws_size,
                              hipStream_t stream) {
    const float* x     = (const float*)d_in[0];  // [B,2]
    const float* rgb   = (const float*)d_in[1];  // [N,3]
    const float* mu    = (const float*)d_in[2];  // [N,2]
    const float* scale = (const float*)d_in[3];  // [N,2]
    const float* angle = (const float*)d_in[4];  // [N]

    hipMemsetAsync(d_out, 0, (size_t)out_size * sizeof(float), stream);
    hipLaunchKernelGGL(splat_kernel, dim3(NBLK), dim3(TPB), 0, stream,
                       (const float2*)x, rgb, mu, scale, angle, (float*)d_out);
}